// Round 16
// baseline (115.515 us; speedup 1.0000x reference)
//
#include <hip/hip_runtime.h>
#include <hip/hip_bf16.h>

#define B_ 8
#define S_ 2048
#define F_ 1024
#define DK_ 128
#define M_ (B_*S_)          // 16384

typedef unsigned short u16;
typedef short short8 __attribute__((ext_vector_type(8)));
typedef float f32x4 __attribute__((ext_vector_type(4)));
typedef float f32x16 __attribute__((ext_vector_type(16)));

__device__ __forceinline__ u16 f2bf(float f) {
    unsigned int u = __float_as_uint(f);
    u += 0x7FFFu + ((u >> 16) & 1u);    // round-to-nearest-even
    return (u16)(u >> 16);
}
__device__ __forceinline__ unsigned int pack2(float a, float b) {
    return (unsigned int)f2bf(a) | ((unsigned int)f2bf(b) << 16);
}
__device__ __forceinline__ float fexp2(float x) {
#if __has_builtin(__builtin_amdgcn_exp2f)
    return __builtin_amdgcn_exp2f(x);   // raw v_exp_f32 (2^x)
#else
    return exp2f(x);
#endif
}
__device__ __forceinline__ unsigned int cvt_pk_bf16(float lo, float hi) {
    unsigned int r;
    asm("v_cvt_pk_bf16_f32 %0, %1, %2" : "=v"(r) : "v"(lo), "v"(hi));
    return r;
}
// v_permlane32_swap_b32 a, b:  a_hi <-> b_lo.
__device__ __forceinline__ void pl32_swap(unsigned int& a, unsigned int& b) {
    asm("v_permlane32_swap_b32 %0, %1" : "+v"(a), "+v"(b));
}

// ---------------------------------------------------------------------------
// Kernel 1: W [1024][128] fp32 -> WT [3][128][1024] bf16 (transposed).
// w_q gets (1/sqrt(128)) * log2(e) folded in, so softmax uses raw exp2.
// ---------------------------------------------------------------------------
__global__ __launch_bounds__(256) void prep_wt(const float* __restrict__ wq,
                                               const float* __restrict__ wk,
                                               const float* __restrict__ wv,
                                               u16* __restrict__ WT) {
    int id = blockIdx.x * 256 + threadIdx.x;
    if (id >= 3 * DK_ * F_) return;
    int m   = id / (DK_ * F_);
    int rem = id - m * (DK_ * F_);
    int c   = rem / F_;
    int k   = rem - c * F_;
    const float* w = (m == 0) ? wq : (m == 1) ? wk : wv;
    float v = w[k * DK_ + c];
    if (m == 0) v *= 0.12751741951f;   // (1/sqrt(128)) * log2(e)
    WT[id] = f2bf(v);
}

// ---------------------------------------------------------------------------
// Kernel 2: projection GEMM (R2-R6 MFMA core) writing MFMA-FRAGMENT layouts:
//   mode 0/1 (Q,K):  frag[g][c][lane][e] = X[g*32+(lane&31)][c*16+(lane>>5)*8+e]
//                    (g = 32-row block, c = 16-d chunk; 1KB contiguous/fragment)
//   mode 2   (V):    frag[g][ct][ch][lane][e] =
//                    V^T[ct*32+(lane&31)][g*32+ch*16+(lane>>5)*8+e]
// so attn's per-wave fragment loads are single coalesced dwordx4 (no LDS).
// One dispatch per mode (profiling visibility + identical math).
// ---------------------------------------------------------------------------
__global__ __launch_bounds__(256, 3) void proj(const float* __restrict__ X,
                                               const u16* __restrict__ WT,
                                               const int mode,
                                               u16* __restrict__ qfr,
                                               u16* __restrict__ kfr,
                                               u16* __restrict__ vfr) {
    const u16* W = WT + mode * (DK_ * F_);

    __shared__ u16 a_lds[64][40];
    __shared__ u16 w_lds[128][40];

    const int t    = threadIdx.x;
    const int lane = t & 63;
    const int wv_  = t >> 6;
    const int l15  = lane & 15, l4 = lane >> 4;
    const int row0 = blockIdx.x * 64;

    f32x4 acc[8];
#pragma unroll
    for (int j = 0; j < 8; ++j) acc[j] = f32x4{0.f, 0.f, 0.f, 0.f};

    for (int k0 = 0; k0 < F_; k0 += 32) {
        {
            int r = t >> 2, kk = (t & 3) * 8;
            const float4* src = (const float4*)(X + (size_t)(row0 + r) * F_ + k0 + kk);
            float4 f0 = src[0], f1 = src[1];
            int4 o0;
            o0.x = pack2(f0.x, f0.y); o0.y = pack2(f0.z, f0.w);
            o0.z = pack2(f1.x, f1.y); o0.w = pack2(f1.z, f1.w);
            *(int4*)&a_lds[r][kk] = o0;
        }
        {
            int c = t >> 1, kk = (t & 1) * 16;
            const int4* src = (const int4*)(W + (size_t)c * F_ + k0 + kk);
            *(int4*)&w_lds[c][kk]     = src[0];
            *(int4*)&w_lds[c][kk + 8] = src[1];
        }
        __syncthreads();

        short8 af = *(const short8*)&a_lds[wv_ * 16 + l15][l4 * 8];
        short8 bf[8];
#pragma unroll
        for (int ct = 0; ct < 8; ++ct)
            bf[ct] = *(const short8*)&w_lds[ct * 16 + l15][l4 * 8];

        if (mode < 2) {
#pragma unroll
            for (int ct = 0; ct < 8; ++ct)
                acc[ct] = __builtin_amdgcn_mfma_f32_16x16x32_bf16(af, bf[ct], acc[ct], 0, 0, 0);
        } else {
#pragma unroll
            for (int ct = 0; ct < 8; ++ct)
                acc[ct] = __builtin_amdgcn_mfma_f32_16x16x32_bf16(bf[ct], af, acc[ct], 0, 0, 0);
        }
        __syncthreads();
    }

    if (mode < 2) {
        u16* OUT = (mode == 0) ? qfr : kfr;
#pragma unroll
        for (int ct = 0; ct < 8; ++ct)
#pragma unroll
            for (int r = 0; r < 4; ++r) {
                int q = row0 + wv_ * 16 + l4 * 4 + r;     // row (q or kv)
                int d = ct * 16 + l15;                    // col
                int g = q >> 5, j = q & 31;
                int c = d >> 4, h2 = (d >> 3) & 1, e = d & 7;
                OUT[(((size_t)g * 8 + c) * 64 + h2 * 32 + j) * 8 + e] = f2bf(acc[ct][r]);
            }
    } else {
#pragma unroll
        for (int ct = 0; ct < 8; ++ct)
#pragma unroll
            for (int r = 0; r < 4; ++r) {
                int d = ct * 16 + l4 * 4 + r;             // C row = W col = d
                int m = row0 + wv_ * 16 + l15;            // C col = kv
                int g = m >> 5, ch = (m >> 4) & 1, h2 = (m >> 3) & 1, e = m & 7;
                int ct2 = d >> 5, l31 = d & 31;
                vfr[((((size_t)g * 4 + ct2) * 2 + ch) * 64 + h2 * 32 + l31) * 8 + e]
                    = f2bf(acc[ct][r]);
            }
    }
}

// ---------------------------------------------------------------------------
// Kernel 3: flash attention v7 — NO LDS in the loop.
// R15's floor analysis: per CU-iter, LDS instrs (192 x 12cyc) + writes +
// MFMA + softmax + staging L2 SUM to ~4700cyc (observed) because 2 barriers
// per iter phase-lock all 8 waves.  v7: Q/K/V live in global memory already
// in fragment order (proj writes them swizzled), so every fragment load is
// one coalesced dwordx4 from the XCD-pinned L2.  Zero staging, zero in-loop
// barriers: waves fully independent, 16-deep load ILP per iter, L1 catches
// the q_sub-pair duplicates.  Math/epilogue byte-identical to R15.
// 8 waves = q_sub(2) x kv_sub(4), q-tile 64, kv-tile 128, 16 iters.
// ---------------------------------------------------------------------------
__global__ __launch_bounds__(512)
__attribute__((amdgpu_waves_per_eu(2)))
void attn(const u16* __restrict__ qfr,
          const u16* __restrict__ kfr,
          const u16* __restrict__ vfr,
          float* __restrict__ out) {
    __shared__ float ob[64][132];
    __shared__ float m_l[2][4][32], l_l[2][4][2][32], gm_l[2][32], gl_l[2][32];

    const int t      = threadIdx.x;
    const int lane   = t & 63;
    const int wv_    = t >> 6;              // 0..7
    const int q_sub  = wv_ & 1;
    const int kv_sub = wv_ >> 1;            // 0..3
    const int r31    = lane & 31;
    const int hi     = lane >> 5;

    const int b  = blockIdx.x & 7;
    const int qi = blockIdx.x >> 3;          // 0..31
    const int qrow0 = b * S_ + qi * 64;

    // Q fragments (coalesced: 1KB per instr)
    const size_t qg = (size_t)(b * 64 + qi * 2 + q_sub);
    short8 qf[8];
#pragma unroll
    for (int c = 0; c < 8; ++c)
        qf[c] = *(const short8*)(qfr + (qg * 8 + c) * 512 + lane * 8);

    f32x16 o4[4];
#pragma unroll
    for (int ct = 0; ct < 4; ++ct)
#pragma unroll
        for (int i = 0; i < 16; ++i) o4[ct][i] = 0.f;
    float mrun = -1.0e30f, lrun = 0.f;      // mrun cross-half uniform; lrun per-half

    // prologue: K fragments for kt=0
    short8 kf[8];
    {
        const size_t g0 = (size_t)(b * 64 + kv_sub);
#pragma unroll
        for (int c = 0; c < 8; ++c)
            kf[c] = *(const short8*)(kfr + (g0 * 8 + c) * 512 + lane * 8);
    }

    for (int kt = 0; kt < 16; ++kt) {
        const size_t g = (size_t)(b * 64 + kt * 4 + kv_sub);

        // ---- QK^T (own quarter), two independent 4-chains then add
        f32x16 sa, sb;
#pragma unroll
        for (int i = 0; i < 16; ++i) { sa[i] = 0.f; sb[i] = 0.f; }
#pragma unroll
        for (int c = 0; c < 4; ++c) {
            sa = __builtin_amdgcn_mfma_f32_32x32x16_bf16(kf[c],     qf[c],     sa, 0, 0, 0);
            sb = __builtin_amdgcn_mfma_f32_32x32x16_bf16(kf[c + 4], qf[c + 4], sb, 0, 0, 0);
        }
        f32x16 st;
#pragma unroll
        for (int i = 0; i < 16; ++i) st[i] = sa[i] + sb[i];

        // ---- V fragments issued now; land under softmax (coalesced dwordx4)
        short8 vf[4][2];
#pragma unroll
        for (int ct = 0; ct < 4; ++ct)
#pragma unroll
            for (int ch = 0; ch < 2; ++ch)
                vf[ct][ch] = *(const short8*)(vfr + (((g * 4 + ct) * 2 + ch) * 64 + lane) * 8);

        // ---- per-lane softmax (log2 units), cross-lane only in rare defer path
        float tm = st[0];
#pragma unroll
        for (int i = 1; i < 16; ++i) tm = fmaxf(tm, st[i]);
        if (__any(tm > mrun + 8.0f)) {
            tm = fmaxf(tm, __shfl_xor(tm, 32, 64));   // make mrun half-uniform
            float mn = fmaxf(mrun, tm);
            float fs = fexp2(mrun - mn);
            mrun = mn;
            lrun *= fs;
#pragma unroll
            for (int ct = 0; ct < 4; ++ct)
#pragma unroll
                for (int i = 0; i < 16; ++i) o4[ct][i] *= fs;
        }
        float s0 = 0.f, s1 = 0.f;
#pragma unroll
        for (int i = 0; i < 16; i += 2) {
            st[i]     = fexp2(st[i] - mrun);
            st[i + 1] = fexp2(st[i + 1] - mrun);
            s0 += st[i]; s1 += st[i + 1];
        }
        lrun += s0 + s1;

        // ---- P -> bf16 B-fragments via permlane32_swap
        short8 bp[2];
#pragma unroll
        for (int ch = 0; ch < 2; ++ch) {
            unsigned int A1 = cvt_pk_bf16(st[ch * 8 + 0], st[ch * 8 + 1]);
            unsigned int A2 = cvt_pk_bf16(st[ch * 8 + 2], st[ch * 8 + 3]);
            unsigned int A3 = cvt_pk_bf16(st[ch * 8 + 4], st[ch * 8 + 5]);
            unsigned int A4 = cvt_pk_bf16(st[ch * 8 + 6], st[ch * 8 + 7]);
            pl32_swap(A1, A3);
            pl32_swap(A2, A4);
            int4 w;
            w.x = (int)A1; w.y = (int)A2; w.z = (int)A3; w.w = (int)A4;
            bp[ch] = *(short8*)&w;
        }

        // ---- prefetch next K fragments (kf regs free); land under PV
        if (kt < 15) {
            const size_t gn = (size_t)(b * 64 + (kt + 1) * 4 + kv_sub);
#pragma unroll
            for (int c = 0; c < 8; ++c)
                kf[c] = *(const short8*)(kfr + (gn * 8 + c) * 512 + lane * 8);
        }

        // ---- PV: full d per wave, k-dim = this wave's 32-kv slice
#pragma unroll
        for (int ct = 0; ct < 4; ++ct) {
            o4[ct] = __builtin_amdgcn_mfma_f32_32x32x16_bf16(vf[ct][0], bp[0], o4[ct], 0, 0, 0);
            o4[ct] = __builtin_amdgcn_mfma_f32_32x32x16_bf16(vf[ct][1], bp[1], o4[ct], 0, 0, 0);
        }
    }

    // ---- epilogue: combine 4 kv_sub partials per q_sub ----
    __syncthreads();
    l_l[q_sub][kv_sub][hi][r31] = lrun;
    if (lane < 32) m_l[q_sub][kv_sub][r31] = mrun;
    __syncthreads();
    if (t < 64) {
        int qs = t >> 5, qq = t & 31;
        float gm = -1.0e30f;
#pragma unroll
        for (int ks = 0; ks < 4; ++ks) gm = fmaxf(gm, m_l[qs][ks][qq]);
        float gl = 0.f;
#pragma unroll
        for (int ks = 0; ks < 4; ++ks)
            gl += (l_l[qs][ks][0][qq] + l_l[qs][ks][1][qq]) * fexp2(m_l[qs][ks][qq] - gm);
        gm_l[qs][qq] = gm;
        gl_l[qs][qq] = gl;
    }
    __syncthreads();

    const float sc = fexp2(mrun - gm_l[q_sub][r31]);
    const int qrow = q_sub * 32 + r31;
    for (int rr = 0; rr < 4; ++rr) {
        if (kv_sub == rr) {
            if (rr == 0) {
#pragma unroll
                for (int ct = 0; ct < 4; ++ct)
#pragma unroll
                    for (int i = 0; i < 16; ++i) {
                        int d = ct * 32 + (i & 3) + 8 * (i >> 2) + 4 * hi;
                        ob[qrow][d] = o4[ct][i] * sc;
                    }
            } else {
#pragma unroll
                for (int ct = 0; ct < 4; ++ct)
#pragma unroll
                    for (int i = 0; i < 16; ++i) {
                        int d = ct * 32 + (i & 3) + 8 * (i >> 2) + 4 * hi;
                        ob[qrow][d] += o4[ct][i] * sc;
                    }
            }
        }
        __syncthreads();
    }

    // ---- final store: thread t -> row t>>3 (0..63), cols (t&7)*16..+16
    {
        int row = t >> 3, d0 = (t & 7) * 16;
        float inv = 1.0f / gl_l[row >> 5][row & 31];
        float* dst = out + (size_t)(qrow0 + row) * DK_ + d0;
#pragma unroll
        for (int j = 0; j < 16; j += 4) {
            float4 v;
            v.x = ob[row][d0 + j]     * inv;
            v.y = ob[row][d0 + j + 1] * inv;
            v.z = ob[row][d0 + j + 2] * inv;
            v.w = ob[row][d0 + j + 3] * inv;
            *(float4*)(dst + j) = v;
        }
    }
}

// ---------------------------------------------------------------------------
extern "C" void kernel_launch(void* const* d_in, const int* in_sizes, int n_in,
                              void* d_out, int out_size, void* d_ws, size_t ws_size,
                              hipStream_t stream) {
    const float* q  = (const float*)d_in[0];
    const float* k  = (const float*)d_in[1];
    const float* v  = (const float*)d_in[2];
    const float* wq = (const float*)d_in[3];
    const float* wk = (const float*)d_in[4];
    const float* wv = (const float*)d_in[5];
    float* out = (float*)d_out;

    char* ws = (char*)d_ws;
    u16* WT  = (u16*)ws;                                   // 786432 B
    u16* qfr = (u16*)(ws + 786432);                        // 4 MB (fragment layout)
    u16* kfr = (u16*)(ws + 786432 + 4194304);              // 4 MB
    u16* vfr = (u16*)(ws + 786432 + 2 * 4194304);          // 4 MB

    prep_wt<<<dim3(1536), dim3(256), 0, stream>>>(wq, wk, wv, WT);
    proj<<<dim3(256), dim3(256), 0, stream>>>(q, WT, 0, qfr, kfr, vfr);
    proj<<<dim3(256), dim3(256), 0, stream>>>(k, WT, 1, qfr, kfr, vfr);
    proj<<<dim3(256), dim3(256), 0, stream>>>(v, WT, 2, qfr, kfr, vfr);
    attn<<<dim3(256), dim3(512), 0, stream>>>(qfr, kfr, vfr, out);
}

// Round 17
// 70.639 us; speedup vs baseline: 1.6353x; 1.6353x over previous
//
#include <hip/hip_runtime.h>
#include <hip/hip_bf16.h>

#define B_ 8
#define S_ 2048
#define F_ 1024
#define DK_ 128
#define M_ (B_*S_)          // 16384

typedef unsigned short u16;
typedef short short8 __attribute__((ext_vector_type(8)));
typedef float f32x4 __attribute__((ext_vector_type(4)));
typedef float f32x16 __attribute__((ext_vector_type(16)));

__device__ __forceinline__ u16 f2bf(float f) {
    unsigned int u = __float_as_uint(f);
    u += 0x7FFFu + ((u >> 16) & 1u);    // round-to-nearest-even
    return (u16)(u >> 16);
}
__device__ __forceinline__ unsigned int pack2(float a, float b) {
    return (unsigned int)f2bf(a) | ((unsigned int)f2bf(b) << 16);
}
__device__ __forceinline__ float fexp2(float x) {
#if __has_builtin(__builtin_amdgcn_exp2f)
    return __builtin_amdgcn_exp2f(x);   // raw v_exp_f32 (2^x)
#else
    return exp2f(x);
#endif
}
__device__ __forceinline__ unsigned int cvt_pk_bf16(float lo, float hi) {
    unsigned int r;
    asm("v_cvt_pk_bf16_f32 %0, %1, %2" : "=v"(r) : "v"(lo), "v"(hi));
    return r;
}
// v_permlane32_swap_b32 a, b:  a_hi <-> b_lo.
__device__ __forceinline__ void pl32_swap(unsigned int& a, unsigned int& b) {
    asm("v_permlane32_swap_b32 %0, %1" : "+v"(a), "+v"(b));
}

// ---------------------------------------------------------------------------
// Kernel 1: W [1024][128] fp32 -> WT [3][128][1024] bf16 (transposed).
// w_q gets (1/sqrt(128)) * log2(e) folded in, so softmax uses raw exp2.
// ---------------------------------------------------------------------------
__global__ __launch_bounds__(256) void prep_wt(const float* __restrict__ wq,
                                               const float* __restrict__ wk,
                                               const float* __restrict__ wv,
                                               u16* __restrict__ WT) {
    int id = blockIdx.x * 256 + threadIdx.x;
    if (id >= 3 * DK_ * F_) return;
    int m   = id / (DK_ * F_);
    int rem = id - m * (DK_ * F_);
    int c   = rem / F_;
    int k   = rem - c * F_;
    const float* w = (m == 0) ? wq : (m == 1) ? wk : wv;
    float v = w[k * DK_ + c];
    if (m == 0) v *= 0.12751741951f;   // (1/sqrt(128)) * log2(e)
    WT[id] = f2bf(v);
}

// ---------------------------------------------------------------------------
// Kernel 2: projection GEMM — R15's SINGLE-dispatch driver (grid (256,3),
// 768 blocks = 3 blocks/CU; R16's 3x256-block split serialized three
// 1-block/CU latency-bound dispatches = +60us, reverted) with R16's
// MFMA-FRAGMENT epilogue:
//   mode 0/1 (Q,K):  frag[g][c][lane][e] = X[g*32+(lane&31)][c*16+(lane>>5)*8+e]
//   mode 2   (V):    frag[g][ct][ch][lane][e] =
//                    V^T[ct*32+(lane&31)][g*32+ch*16+(lane>>5)*8+e]
// so attn's per-wave fragment loads are single coalesced dwordx4 (no LDS).
// ---------------------------------------------------------------------------
__global__ __launch_bounds__(256, 3) void proj(const float* __restrict__ xq,
                                               const float* __restrict__ xk,
                                               const float* __restrict__ xv,
                                               const u16* __restrict__ WT,
                                               u16* __restrict__ qfr,
                                               u16* __restrict__ kfr,
                                               u16* __restrict__ vfr) {
    const int mode = blockIdx.y;
    const float* X = (mode == 0) ? xq : (mode == 1) ? xk : xv;
    const u16*   W = WT + mode * (DK_ * F_);

    __shared__ u16 a_lds[64][40];
    __shared__ u16 w_lds[128][40];

    const int t    = threadIdx.x;
    const int lane = t & 63;
    const int wv_  = t >> 6;
    const int l15  = lane & 15, l4 = lane >> 4;
    const int row0 = blockIdx.x * 64;

    f32x4 acc[8];
#pragma unroll
    for (int j = 0; j < 8; ++j) acc[j] = f32x4{0.f, 0.f, 0.f, 0.f};

    for (int k0 = 0; k0 < F_; k0 += 32) {
        {
            int r = t >> 2, kk = (t & 3) * 8;
            const float4* src = (const float4*)(X + (size_t)(row0 + r) * F_ + k0 + kk);
            float4 f0 = src[0], f1 = src[1];
            int4 o0;
            o0.x = pack2(f0.x, f0.y); o0.y = pack2(f0.z, f0.w);
            o0.z = pack2(f1.x, f1.y); o0.w = pack2(f1.z, f1.w);
            *(int4*)&a_lds[r][kk] = o0;
        }
        {
            int c = t >> 1, kk = (t & 1) * 16;
            const int4* src = (const int4*)(W + (size_t)c * F_ + k0 + kk);
            *(int4*)&w_lds[c][kk]     = src[0];
            *(int4*)&w_lds[c][kk + 8] = src[1];
        }
        __syncthreads();

        short8 af = *(const short8*)&a_lds[wv_ * 16 + l15][l4 * 8];
        short8 bf[8];
#pragma unroll
        for (int ct = 0; ct < 8; ++ct)
            bf[ct] = *(const short8*)&w_lds[ct * 16 + l15][l4 * 8];

        if (mode < 2) {
#pragma unroll
            for (int ct = 0; ct < 8; ++ct)
                acc[ct] = __builtin_amdgcn_mfma_f32_16x16x32_bf16(af, bf[ct], acc[ct], 0, 0, 0);
        } else {
#pragma unroll
            for (int ct = 0; ct < 8; ++ct)
                acc[ct] = __builtin_amdgcn_mfma_f32_16x16x32_bf16(bf[ct], af, acc[ct], 0, 0, 0);
        }
        __syncthreads();
    }

    if (mode < 2) {
        u16* OUT = (mode == 0) ? qfr : kfr;
#pragma unroll
        for (int ct = 0; ct < 8; ++ct)
#pragma unroll
            for (int r = 0; r < 4; ++r) {
                int q = row0 + wv_ * 16 + l4 * 4 + r;     // row (q or kv)
                int d = ct * 16 + l15;                    // col
                int g = q >> 5, j = q & 31;
                int c = d >> 4, h2 = (d >> 3) & 1, e = d & 7;
                OUT[(((size_t)g * 8 + c) * 64 + h2 * 32 + j) * 8 + e] = f2bf(acc[ct][r]);
            }
    } else {
#pragma unroll
        for (int ct = 0; ct < 8; ++ct)
#pragma unroll
            for (int r = 0; r < 4; ++r) {
                int d = ct * 16 + l4 * 4 + r;             // C row = W col = d
                int m = row0 + wv_ * 16 + l15;            // C col = kv
                int g = m >> 5, ch = (m >> 4) & 1, h2 = (m >> 3) & 1, e = m & 7;
                int ct2 = d >> 5, l31 = d & 31;
                vfr[((((size_t)g * 4 + ct2) * 2 + ch) * 64 + h2 * 32 + l31) * 8 + e]
                    = f2bf(acc[ct][r]);
            }
    }
}

// ---------------------------------------------------------------------------
// Kernel 3: flash attention v7 — NO LDS in the loop (byte-identical to R16).
// Q/K/V in fragment order in L2; every fragment load one coalesced dwordx4;
// zero staging, zero in-loop barriers; waves fully independent.
// 8 waves = q_sub(2) x kv_sub(4), q-tile 64, kv-tile 128, 16 iters.
// ---------------------------------------------------------------------------
__global__ __launch_bounds__(512)
__attribute__((amdgpu_waves_per_eu(2)))
void attn(const u16* __restrict__ qfr,
          const u16* __restrict__ kfr,
          const u16* __restrict__ vfr,
          float* __restrict__ out) {
    __shared__ float ob[64][132];
    __shared__ float m_l[2][4][32], l_l[2][4][2][32], gm_l[2][32], gl_l[2][32];

    const int t      = threadIdx.x;
    const int lane   = t & 63;
    const int wv_    = t >> 6;              // 0..7
    const int q_sub  = wv_ & 1;
    const int kv_sub = wv_ >> 1;            // 0..3
    const int r31    = lane & 31;
    const int hi     = lane >> 5;

    const int b  = blockIdx.x & 7;
    const int qi = blockIdx.x >> 3;          // 0..31
    const int qrow0 = b * S_ + qi * 64;

    // Q fragments (coalesced: 1KB per instr)
    const size_t qg = (size_t)(b * 64 + qi * 2 + q_sub);
    short8 qf[8];
#pragma unroll
    for (int c = 0; c < 8; ++c)
        qf[c] = *(const short8*)(qfr + (qg * 8 + c) * 512 + lane * 8);

    f32x16 o4[4];
#pragma unroll
    for (int ct = 0; ct < 4; ++ct)
#pragma unroll
        for (int i = 0; i < 16; ++i) o4[ct][i] = 0.f;
    float mrun = -1.0e30f, lrun = 0.f;      // mrun cross-half uniform; lrun per-half

    // prologue: K fragments for kt=0
    short8 kf[8];
    {
        const size_t g0 = (size_t)(b * 64 + kv_sub);
#pragma unroll
        for (int c = 0; c < 8; ++c)
            kf[c] = *(const short8*)(kfr + (g0 * 8 + c) * 512 + lane * 8);
    }

    for (int kt = 0; kt < 16; ++kt) {
        const size_t g = (size_t)(b * 64 + kt * 4 + kv_sub);

        // ---- QK^T (own quarter), two independent 4-chains then add
        f32x16 sa, sb;
#pragma unroll
        for (int i = 0; i < 16; ++i) { sa[i] = 0.f; sb[i] = 0.f; }
#pragma unroll
        for (int c = 0; c < 4; ++c) {
            sa = __builtin_amdgcn_mfma_f32_32x32x16_bf16(kf[c],     qf[c],     sa, 0, 0, 0);
            sb = __builtin_amdgcn_mfma_f32_32x32x16_bf16(kf[c + 4], qf[c + 4], sb, 0, 0, 0);
        }
        f32x16 st;
#pragma unroll
        for (int i = 0; i < 16; ++i) st[i] = sa[i] + sb[i];

        // ---- V fragments issued now; land under softmax (coalesced dwordx4)
        short8 vf[4][2];
#pragma unroll
        for (int ct = 0; ct < 4; ++ct)
#pragma unroll
            for (int ch = 0; ch < 2; ++ch)
                vf[ct][ch] = *(const short8*)(vfr + (((g * 4 + ct) * 2 + ch) * 64 + lane) * 8);

        // ---- per-lane softmax (log2 units), cross-lane only in rare defer path
        float tm = st[0];
#pragma unroll
        for (int i = 1; i < 16; ++i) tm = fmaxf(tm, st[i]);
        if (__any(tm > mrun + 8.0f)) {
            tm = fmaxf(tm, __shfl_xor(tm, 32, 64));   // make mrun half-uniform
            float mn = fmaxf(mrun, tm);
            float fs = fexp2(mrun - mn);
            mrun = mn;
            lrun *= fs;
#pragma unroll
            for (int ct = 0; ct < 4; ++ct)
#pragma unroll
                for (int i = 0; i < 16; ++i) o4[ct][i] *= fs;
        }
        float s0 = 0.f, s1 = 0.f;
#pragma unroll
        for (int i = 0; i < 16; i += 2) {
            st[i]     = fexp2(st[i] - mrun);
            st[i + 1] = fexp2(st[i + 1] - mrun);
            s0 += st[i]; s1 += st[i + 1];
        }
        lrun += s0 + s1;

        // ---- P -> bf16 B-fragments via permlane32_swap
        short8 bp[2];
#pragma unroll
        for (int ch = 0; ch < 2; ++ch) {
            unsigned int A1 = cvt_pk_bf16(st[ch * 8 + 0], st[ch * 8 + 1]);
            unsigned int A2 = cvt_pk_bf16(st[ch * 8 + 2], st[ch * 8 + 3]);
            unsigned int A3 = cvt_pk_bf16(st[ch * 8 + 4], st[ch * 8 + 5]);
            unsigned int A4 = cvt_pk_bf16(st[ch * 8 + 6], st[ch * 8 + 7]);
            pl32_swap(A1, A3);
            pl32_swap(A2, A4);
            int4 w;
            w.x = (int)A1; w.y = (int)A2; w.z = (int)A3; w.w = (int)A4;
            bp[ch] = *(short8*)&w;
        }

        // ---- prefetch next K fragments (kf regs free); land under PV
        if (kt < 15) {
            const size_t gn = (size_t)(b * 64 + (kt + 1) * 4 + kv_sub);
#pragma unroll
            for (int c = 0; c < 8; ++c)
                kf[c] = *(const short8*)(kfr + (gn * 8 + c) * 512 + lane * 8);
        }

        // ---- PV: full d per wave, k-dim = this wave's 32-kv slice
#pragma unroll
        for (int ct = 0; ct < 4; ++ct) {
            o4[ct] = __builtin_amdgcn_mfma_f32_32x32x16_bf16(vf[ct][0], bp[0], o4[ct], 0, 0, 0);
            o4[ct] = __builtin_amdgcn_mfma_f32_32x32x16_bf16(vf[ct][1], bp[1], o4[ct], 0, 0, 0);
        }
    }

    // ---- epilogue: combine 4 kv_sub partials per q_sub ----
    __syncthreads();
    l_l[q_sub][kv_sub][hi][r31] = lrun;
    if (lane < 32) m_l[q_sub][kv_sub][r31] = mrun;
    __syncthreads();
    if (t < 64) {
        int qs = t >> 5, qq = t & 31;
        float gm = -1.0e30f;
#pragma unroll
        for (int ks = 0; ks < 4; ++ks) gm = fmaxf(gm, m_l[qs][ks][qq]);
        float gl = 0.f;
#pragma unroll
        for (int ks = 0; ks < 4; ++ks)
            gl += (l_l[qs][ks][0][qq] + l_l[qs][ks][1][qq]) * fexp2(m_l[qs][ks][qq] - gm);
        gm_l[qs][qq] = gm;
        gl_l[qs][qq] = gl;
    }
    __syncthreads();

    const float sc = fexp2(mrun - gm_l[q_sub][r31]);
    const int qrow = q_sub * 32 + r31;
    for (int rr = 0; rr < 4; ++rr) {
        if (kv_sub == rr) {
            if (rr == 0) {
#pragma unroll
                for (int ct = 0; ct < 4; ++ct)
#pragma unroll
                    for (int i = 0; i < 16; ++i) {
                        int d = ct * 32 + (i & 3) + 8 * (i >> 2) + 4 * hi;
                        ob[qrow][d] = o4[ct][i] * sc;
                    }
            } else {
#pragma unroll
                for (int ct = 0; ct < 4; ++ct)
#pragma unroll
                    for (int i = 0; i < 16; ++i) {
                        int d = ct * 32 + (i & 3) + 8 * (i >> 2) + 4 * hi;
                        ob[qrow][d] += o4[ct][i] * sc;
                    }
            }
        }
        __syncthreads();
    }

    // ---- final store: thread t -> row t>>3 (0..63), cols (t&7)*16..+16
    {
        int row = t >> 3, d0 = (t & 7) * 16;
        float inv = 1.0f / gl_l[row >> 5][row & 31];
        float* dst = out + (size_t)(qrow0 + row) * DK_ + d0;
#pragma unroll
        for (int j = 0; j < 16; j += 4) {
            float4 v;
            v.x = ob[row][d0 + j]     * inv;
            v.y = ob[row][d0 + j + 1] * inv;
            v.z = ob[row][d0 + j + 2] * inv;
            v.w = ob[row][d0 + j + 3] * inv;
            *(float4*)(dst + j) = v;
        }
    }
}

// ---------------------------------------------------------------------------
extern "C" void kernel_launch(void* const* d_in, const int* in_sizes, int n_in,
                              void* d_out, int out_size, void* d_ws, size_t ws_size,
                              hipStream_t stream) {
    const float* q  = (const float*)d_in[0];
    const float* k  = (const float*)d_in[1];
    const float* v  = (const float*)d_in[2];
    const float* wq = (const float*)d_in[3];
    const float* wk = (const float*)d_in[4];
    const float* wv = (const float*)d_in[5];
    float* out = (float*)d_out;

    char* ws = (char*)d_ws;
    u16* WT  = (u16*)ws;                                   // 786432 B
    u16* qfr = (u16*)(ws + 786432);                        // 4 MB (fragment layout)
    u16* kfr = (u16*)(ws + 786432 + 4194304);              // 4 MB
    u16* vfr = (u16*)(ws + 786432 + 2 * 4194304);          // 4 MB

    prep_wt<<<dim3(1536), dim3(256), 0, stream>>>(wq, wk, wv, WT);
    proj<<<dim3(256, 3), dim3(256), 0, stream>>>(q, k, v, WT, qfr, kfr, vfr);
    attn<<<dim3(256), dim3(512), 0, stream>>>(qfr, kfr, vfr, out);
}